// Round 1
// baseline (1032.900 us; speedup 1.0000x reference)
//
#include <hip/hip_runtime.h>
#include <math.h>

// ---------------- generic f32 GEMM: C[M,N] = A[M,K] (lda) @ B[K,N] (ldb) + bias ----------------
#define BM 64
#define BN 64
#define BK 16

__global__ __launch_bounds__(256) void gemm_f32(
    const float* __restrict__ A, int lda,
    const float* __restrict__ B, int ldb,
    const float* __restrict__ bias,
    float* __restrict__ C, int ldc,
    int M, int N, int K)
{
    __shared__ float As[BM][BK + 1];
    __shared__ float Bs[BK][BN];
    const int t  = threadIdx.x;
    const int tx = t & 15;
    const int ty = t >> 4;
    const int bm = blockIdx.x * BM;
    const int bn = blockIdx.y * BN;

    const int arow = t >> 2;         // 0..63
    const int akg  = (t & 3) << 2;   // 0,4,8,12
    const int bkk  = t >> 4;         // 0..15
    const int bcg  = (t & 15) << 2;  // 0..60

    float acc[4][4];
    #pragma unroll
    for (int r = 0; r < 4; ++r)
        #pragma unroll
        for (int c = 0; c < 4; ++c) acc[r][c] = 0.f;

    for (int k0 = 0; k0 < K; k0 += BK) {
        float4 av = make_float4(0.f, 0.f, 0.f, 0.f);
        if (bm + arow < M)
            av = *(const float4*)(A + (size_t)(bm + arow) * lda + (k0 + akg));
        As[arow][akg + 0] = av.x;
        As[arow][akg + 1] = av.y;
        As[arow][akg + 2] = av.z;
        As[arow][akg + 3] = av.w;

        float4 bv;
        const float* Brow = B + (size_t)(k0 + bkk) * ldb;
        int bcol = bn + bcg;
        if (bcol + 3 < N) {
            bv = *(const float4*)(Brow + bcol);
        } else {
            bv.x = (bcol + 0 < N) ? Brow[bcol + 0] : 0.f;
            bv.y = (bcol + 1 < N) ? Brow[bcol + 1] : 0.f;
            bv.z = (bcol + 2 < N) ? Brow[bcol + 2] : 0.f;
            bv.w = (bcol + 3 < N) ? Brow[bcol + 3] : 0.f;
        }
        *(float4*)(&Bs[bkk][bcg]) = bv;
        __syncthreads();

        #pragma unroll
        for (int kk = 0; kk < BK; ++kk) {
            float a0 = As[ty * 4 + 0][kk];
            float a1 = As[ty * 4 + 1][kk];
            float a2 = As[ty * 4 + 2][kk];
            float a3 = As[ty * 4 + 3][kk];
            float4 b4 = *(const float4*)(&Bs[kk][tx * 4]);
            acc[0][0] += a0 * b4.x; acc[0][1] += a0 * b4.y; acc[0][2] += a0 * b4.z; acc[0][3] += a0 * b4.w;
            acc[1][0] += a1 * b4.x; acc[1][1] += a1 * b4.y; acc[1][2] += a1 * b4.z; acc[1][3] += a1 * b4.w;
            acc[2][0] += a2 * b4.x; acc[2][1] += a2 * b4.y; acc[2][2] += a2 * b4.z; acc[2][3] += a2 * b4.w;
            acc[3][0] += a3 * b4.x; acc[3][1] += a3 * b4.y; acc[3][2] += a3 * b4.z; acc[3][3] += a3 * b4.w;
        }
        __syncthreads();
    }

    #pragma unroll
    for (int r = 0; r < 4; ++r) {
        int row = bm + ty * 4 + r;
        if (row >= M) continue;
        #pragma unroll
        for (int c = 0; c < 4; ++c) {
            int col = bn + tx * 4 + c;
            if (col < N) {
                float b = bias ? bias[col] : 0.f;
                C[(size_t)row * ldc + col] = acc[r][c] + b;
            }
        }
    }
}

// ---------------- build concatenated W for z-projection: [Wb (128x8) | Wdz (128x32)] ----------------
__global__ void build_wcat(const float* __restrict__ Wb, const float* __restrict__ bb,
                           const float* __restrict__ Wdz, const float* __restrict__ bdz,
                           float* __restrict__ wcat, float* __restrict__ bcat)
{
    for (int idx = threadIdx.x; idx < 128 * 40; idx += 256) {
        int c = idx / 40, j = idx % 40;
        wcat[idx] = (j < 8) ? Wb[c * 8 + j] : Wdz[c * 32 + (j - 8)];
    }
    if (threadIdx.x < 40) {
        int j = threadIdx.x;
        bcat[j] = (j < 8) ? bb[j] : bdz[j - 8];
    }
}

// ---------------- k_pts: kpts[n*24 + f] = sum_p tfn[n,128+p*3+(f/8)] * Wkv[p*8+(f%8)] ----------------
__global__ void kpts_kernel(const float* __restrict__ tfn, const float* __restrict__ Wkv,
                            float* __restrict__ kpts, int n)
{
    int t = blockIdx.x * 256 + threadIdx.x;
    if (t >= n * 24) return;
    int node = t / 24, f = t % 24;
    int a = f >> 3;   // xyz component of k_vec
    int b = f & 7;    // point index of k_vec
    const float* vr = tfn + (size_t)node * 176 + 128;
    float s = 0.f;
    #pragma unroll
    for (int p = 0; p < 16; ++p) s += vr[p * 3 + a] * Wkv[p * 8 + b];
    kpts[t] = s;
}

// ---------------- q_pts rotation: qpts[n, hk*3+i] = sum_j rot[n,i,j]*qpraw[n, j*64+hk] + trans[n,i] ----------------
__global__ void qpts_kernel(const float* __restrict__ qpraw, const float* __restrict__ rot,
                            const float* __restrict__ trans, float* __restrict__ qpts, int n)
{
    int t = blockIdx.x * 256 + threadIdx.x;
    if (t >= n * 64) return;
    int node = t / 64, hk = t % 64;
    const float* qr = qpraw + (size_t)node * 192;
    float r0 = qr[hk], r1 = qr[64 + hk], r2 = qr[128 + hk];
    const float* R = rot + (size_t)node * 9;
    const float* T = trans + (size_t)node * 3;
    float* o = qpts + (size_t)node * 192 + hk * 3;
    #pragma unroll
    for (int i = 0; i < 3; ++i)
        o[i] = R[i * 3 + 0] * r0 + R[i * 3 + 1] * r1 + R[i * 3 + 2] * r2 + T[i];
}

// ---------------- CSR build ----------------
__global__ void count_kernel(const int* __restrict__ srcA, int* __restrict__ cnt, int E)
{
    int e = blockIdx.x * 256 + threadIdx.x;
    if (e < E) atomicAdd(&cnt[srcA[e]], 1);
}

__global__ void scan_kernel(const int* __restrict__ cnt, int* __restrict__ off,
                            int* __restrict__ cur, int n)
{
    __shared__ int sums[1024];
    int t = threadIdx.x;
    int chunk = (n + 1023) >> 10;
    int begin = t * chunk;
    int local = 0;
    for (int j = 0; j < chunk; ++j) {
        int i = begin + j;
        if (i < n) local += cnt[i];
    }
    sums[t] = local;
    __syncthreads();
    for (int d = 1; d < 1024; d <<= 1) {
        int x = sums[t];
        int y = (t >= d) ? sums[t - d] : 0;
        __syncthreads();
        sums[t] = x + y;
        __syncthreads();
    }
    int run = sums[t] - local;  // exclusive prefix of this thread's chunk
    for (int j = 0; j < chunk; ++j) {
        int i = begin + j;
        if (i < n) {
            off[i] = run;
            cur[i] = run;
            run += cnt[i];
        }
    }
}

__global__ void fill_kernel(const int* __restrict__ srcA, int* __restrict__ cur,
                            int* __restrict__ elist, int E)
{
    int e = blockIdx.x * 256 + threadIdx.x;
    if (e < E) {
        int s = srcA[e];
        int pos = atomicAdd(&cur[s], 1);
        elist[pos] = e;
    }
}

// ---------------- attention + aggregation: one wave per src node ----------------
// lane = es*8 + h : es = edge slot (0..7), h = head (0..7)
__global__ __launch_bounds__(256) void attn_kernel(
    const int* __restrict__ dstA,
    const int* __restrict__ off, const int* __restrict__ cnt, const int* __restrict__ elist,
    const float* __restrict__ qbuf, const float* __restrict__ kbuf,
    const float* __restrict__ qpts, const float* __restrict__ kpts,
    const float* __restrict__ bpair, const float* __restrict__ mask,
    const float* __restrict__ hwin,
    float* __restrict__ obuf, float* __restrict__ optb, float* __restrict__ opairb,
    int n)
{
    int wave = threadIdx.x >> 6;
    int lane = threadIdx.x & 63;
    int s = blockIdx.x * 4 + wave;
    if (s >= n) return;
    int es = lane >> 3;
    int h  = lane & 7;

    float qh[16];
    {
        const float* qp = qbuf + (size_t)s * 128 + h * 16;
        #pragma unroll
        for (int c = 0; c < 16; ++c) qh[c] = qp[c];
    }
    float qpt[24];
    {
        const float* pp = qpts + (size_t)s * 192 + h * 24;
        #pragma unroll
        for (int j = 0; j < 24; ++j) qpt[j] = pp[j];
    }
    float hwv = log1pf(__expf(hwin[h])) * 0.09622504486493764f;  // softplus * sqrt(1/108)
    float mask_s = mask[s];
    int myoff = off[s], mycnt = cnt[s];

    float ssum = 0.f;
    float oacc[16];
    #pragma unroll
    for (int c = 0; c < 16; ++c) oacc[c] = 0.f;
    float optacc[3] = {0.f, 0.f, 0.f};
    float opacc[32];
    #pragma unroll
    for (int j = 0; j < 32; ++j) opacc[j] = 0.f;

    int nb = (mycnt + 7) >> 3;
    for (int b = 0; b < nb; ++b) {
        int idx = b * 8 + es;
        bool valid = idx < mycnt;
        int e = valid ? elist[myoff + idx] : 0;
        int d = dstA[e];

        const float* kr = kbuf + (size_t)d * 128 + h * 16;
        float4 ka = *(const float4*)(kr + 0);
        float4 kb = *(const float4*)(kr + 4);
        float4 kc = *(const float4*)(kr + 8);
        float4 kd = *(const float4*)(kr + 12);
        float kv[16] = {ka.x, ka.y, ka.z, ka.w, kb.x, kb.y, kb.z, kb.w,
                        kc.x, kc.y, kc.z, kc.w, kd.x, kd.y, kd.z, kd.w};

        const float* kp = kpts + (size_t)d * 24 + h * 3;
        float kp0 = kp[0], kp1 = kp[1], kp2 = kp[2];

        const float* bp = bpair + (size_t)e * 40;
        float bh = bp[h];
        float4 pair4 = *(const float4*)(bp + 8 + h * 4);

        float qk = 0.f;
        #pragma unroll
        for (int c = 0; c < 16; ++c) qk += qh[c] * kv[c];

        float pt = 0.f;
        #pragma unroll
        for (int pp = 0; pp < 8; ++pp) {
            float d0 = qpt[pp * 3 + 0] - kp0;
            float d1 = qpt[pp * 3 + 1] - kp1;
            float d2 = qpt[pp * 3 + 2] - kp2;
            pt += d0 * d0 + d1 * d1 + d2 * d2;
        }

        float md = mask[d];
        float logit = 0.14433756729740643f * qk
                    + 0.5773502691896258f * bh
                    - 0.5f * hwv * pt
                    + 100000.0f * (mask_s * md - 1.0f);
        float w = valid ? __expf(logit) : 0.f;

        ssum += w;
        #pragma unroll
        for (int c = 0; c < 16; ++c) oacc[c] += w * kv[c];
        optacc[0] += w * kp0;
        optacc[1] += w * kp1;
        optacc[2] += w * kp2;

        // o_pair: pair values for this es's edge live on lanes (es, jh), component jc
        #pragma unroll
        for (int jh = 0; jh < 8; ++jh) {
            int srcl = (es << 3) + jh;
            float v0 = __shfl(pair4.x, srcl);
            float v1 = __shfl(pair4.y, srcl);
            float v2 = __shfl(pair4.z, srcl);
            float v3 = __shfl(pair4.w, srcl);
            opacc[jh * 4 + 0] += w * v0;
            opacc[jh * 4 + 1] += w * v1;
            opacc[jh * 4 + 2] += w * v2;
            opacc[jh * 4 + 3] += w * v3;
        }
    }

    // reduce across the 8 edge slots (lane bits 3..5)
    #pragma unroll
    for (int delta = 8; delta <= 32; delta <<= 1) {
        ssum += __shfl_xor(ssum, delta);
        #pragma unroll
        for (int c = 0; c < 16; ++c) oacc[c] += __shfl_xor(oacc[c], delta);
        #pragma unroll
        for (int i = 0; i < 3; ++i) optacc[i] += __shfl_xor(optacc[i], delta);
        #pragma unroll
        for (int j = 0; j < 32; ++j) opacc[j] += __shfl_xor(opacc[j], delta);
    }

    if (es == 0) {
        float inv = 1.f / (ssum + 1e-16f);
        float* op = obuf + (size_t)s * 128 + h * 16;
        #pragma unroll
        for (int c = 0; c < 16; ++c) op[c] = oacc[c] * inv;
        float* pp = optb + (size_t)s * 24 + h * 3;
        #pragma unroll
        for (int i = 0; i < 3; ++i) pp[i] = optacc[i] * inv;
        float* qq = opairb + (size_t)s * 256 + h * 32;
        #pragma unroll
        for (int j = 0; j < 32; ++j) qq[j] = opacc[j] * inv;
    }
}

// ---------------- finalize: rotate o_pt back, norms, assemble feats (N x 416) ----------------
__global__ void finalize_kernel(const float* __restrict__ obuf, const float* __restrict__ optb,
                                const float* __restrict__ opairb,
                                const float* __restrict__ rot, const float* __restrict__ trans,
                                float* __restrict__ feats, int n)
{
    int node = blockIdx.x;
    int t = threadIdx.x;
    float* f = feats + (size_t)node * 416;
    f[160 + t] = opairb[(size_t)node * 256 + t];
    if (t < 128) f[t] = obuf[(size_t)node * 128 + t];
    if (t < 8) {
        int h = t;
        const float* T = trans + (size_t)node * 3;
        const float* R = rot + (size_t)node * 9;
        float v0 = optb[(size_t)node * 24 + h * 3 + 0] - T[0];
        float v1 = optb[(size_t)node * 24 + h * 3 + 1] - T[1];
        float v2 = optb[(size_t)node * 24 + h * 3 + 2] - T[2];
        // out[i] = sum_j rot[j][i] * v[j]
        float r0 = R[0] * v0 + R[3] * v1 + R[6] * v2;
        float r1 = R[1] * v0 + R[4] * v1 + R[7] * v2;
        float r2 = R[2] * v0 + R[5] * v1 + R[8] * v2;
        f[128 + h]      = r0;
        f[136 + h]      = r1;
        f[144 + h]      = r2;
        f[152 + h]      = sqrtf(r0 * r0 + r1 * r1 + r2 * r2 + 1e-8f);
    }
}

// ---------------- host ----------------
extern "C" void kernel_launch(void* const* d_in, const int* in_sizes, int n_in,
                              void* d_out, int out_size, void* d_ws, size_t ws_size,
                              hipStream_t stream)
{
    const float* frame_s = (const float*)d_in[0];
    const float* tfn     = (const float*)d_in[1];
    const float* z       = (const float*)d_in[2];
    const int*   ei      = (const int*)d_in[3];
    const float* mask    = (const float*)d_in[4];
    const float* rot     = (const float*)d_in[5];
    const float* trans   = (const float*)d_in[6];
    const float* Wq      = (const float*)d_in[7];
    const float* bq      = (const float*)d_in[8];
    const float* Wks     = (const float*)d_in[9];
    const float* Wkv     = (const float*)d_in[10];
    const float* Wqp     = (const float*)d_in[11];
    const float* bqp     = (const float*)d_in[12];
    const float* Wb      = (const float*)d_in[13];
    const float* bb      = (const float*)d_in[14];
    const float* Wdz     = (const float*)d_in[15];
    const float* bdz     = (const float*)d_in[16];
    const float* hw      = (const float*)d_in[17];
    const float* Wout    = (const float*)d_in[18];
    const float* bout    = (const float*)d_in[19];
    float* out = (float*)d_out;

    int n = in_sizes[0] / 384;
    int E = in_sizes[3] / 2;
    const int* dstA = ei;        // edge_index[0]
    const int* srcA = ei + E;    // edge_index[1]

    float* ws = (float*)d_ws;
    size_t p = 0;
    auto alloc = [&](size_t elems) -> float* {
        float* r = ws + p;
        p += (elems + 15) & ~((size_t)15);
        return r;
    };
    float* qbuf   = alloc((size_t)n * 128);
    float* kbuf   = alloc((size_t)n * 128);
    float* qpraw  = alloc((size_t)n * 192);
    float* qpts   = alloc((size_t)n * 192);
    float* kpts   = alloc((size_t)n * 24);
    float* obuf   = alloc((size_t)n * 128);
    float* optb   = alloc((size_t)n * 24);
    float* opairb = alloc((size_t)n * 256);
    float* feats  = alloc((size_t)n * 416);
    float* wcat   = alloc(128 * 40);
    float* bcat   = alloc(64);
    float* bpair  = alloc((size_t)E * 40);
    int* cnt   = (int*)alloc((size_t)n);
    int* off   = (int*)alloc((size_t)n);
    int* cur   = (int*)alloc((size_t)n);
    int* elist = (int*)alloc((size_t)E);

    hipMemsetAsync(cnt, 0, (size_t)n * sizeof(int), stream);
    build_wcat<<<1, 256, 0, stream>>>(Wb, bb, Wdz, bdz, wcat, bcat);

    {   // q = frame_s @ Wq + bq
        dim3 g((n + BM - 1) / BM, (128 + BN - 1) / BN);
        gemm_f32<<<g, 256, 0, stream>>>(frame_s, 384, Wq, 128, bq, qbuf, 128, n, 128, 384);
    }
    {   // qp_raw = frame_s @ Wqp + bqp
        dim3 g((n + BM - 1) / BM, (192 + BN - 1) / BN);
        gemm_f32<<<g, 256, 0, stream>>>(frame_s, 384, Wqp, 192, bqp, qpraw, 192, n, 192, 384);
    }
    {   // k = tfn[:, :128] @ Wk_s
        dim3 g((n + BM - 1) / BM, (128 + BN - 1) / BN);
        gemm_f32<<<g, 256, 0, stream>>>(tfn, 176, Wks, 128, nullptr, kbuf, 128, n, 128, 128);
    }
    {   // bpair = z @ [Wb|Wdz] + [bb|bdz]
        dim3 g((E + BM - 1) / BM, 1);
        gemm_f32<<<g, 256, 0, stream>>>(z, 128, wcat, 40, bcat, bpair, 40, E, 40, 128);
    }
    kpts_kernel<<<(n * 24 + 255) / 256, 256, 0, stream>>>(tfn, Wkv, kpts, n);
    qpts_kernel<<<(n * 64 + 255) / 256, 256, 0, stream>>>(qpraw, rot, trans, qpts, n);

    count_kernel<<<(E + 255) / 256, 256, 0, stream>>>(srcA, cnt, E);
    scan_kernel<<<1, 1024, 0, stream>>>(cnt, off, cur, n);
    fill_kernel<<<(E + 255) / 256, 256, 0, stream>>>(srcA, cur, elist, E);

    attn_kernel<<<(n + 3) / 4, 256, 0, stream>>>(dstA, off, cnt, elist,
                                                 qbuf, kbuf, qpts, kpts, bpair, mask, hw,
                                                 obuf, optb, opairb, n);

    finalize_kernel<<<n, 256, 0, stream>>>(obuf, optb, opairb, rot, trans, feats, n);

    {   // out = feats @ Wout + bout
        dim3 g((n + BM - 1) / BM, (384 + BN - 1) / BN);
        gemm_f32<<<g, 256, 0, stream>>>(feats, 416, Wout, 384, bout, out, 384, n, 384, 416);
    }
    (void)n_in; (void)out_size; (void)ws_size;
}

// Round 3
// 907.094 us; speedup vs baseline: 1.1387x; 1.1387x over previous
//
#include <hip/hip_runtime.h>
#include <math.h>

typedef __attribute__((ext_vector_type(8))) short short8;
typedef __attribute__((ext_vector_type(4))) float f32x4;

static __device__ inline unsigned short f2bf(float f) {
    union { float f; unsigned u; } v; v.f = f;
    unsigned r = v.u + 0x7FFF + ((v.u >> 16) & 1);
    return (unsigned short)(r >> 16);
}

// ---------------- MFMA bf16 GEMM: C[M,N] = A[M,K] @ BT[N,K]^T + bias ----------------
// Block tile: 128 x (WJ*32), BK=64. 4 waves in 2x2. Wave tile: 64 x (WJ*16).
template<int WJ>
__global__ __launch_bounds__(256) void gemm_mfma(
    const float* __restrict__ A, int lda,
    const float* __restrict__ BT, int ldb,   // BT is [N][K] row-major
    const float* __restrict__ bias,
    float* __restrict__ C, int ldc,
    int M, int N, int K)
{
    constexpr int GBN = WJ * 32;
    __shared__ unsigned short As[128 * 72];
    __shared__ unsigned short Bs[GBN * 72];

    const int t = threadIdx.x;
    const int wid = t >> 6, lane = t & 63;
    const int wm = (wid & 1) * 64;
    const int wn = (wid >> 1) * (WJ * 16);
    const int row16 = lane & 15, quad = lane >> 4;
    const int bm = blockIdx.x * 128;
    const int bn = blockIdx.y * GBN;

    f32x4 acc[4][WJ];
    #pragma unroll
    for (int i = 0; i < 4; ++i)
        #pragma unroll
        for (int j = 0; j < WJ; ++j)
            #pragma unroll
            for (int r = 0; r < 4; ++r) acc[i][j][r] = 0.f;

    const int ktiles = (K + 63) >> 6;
    for (int kt = 0; kt < ktiles; ++kt) {
        const int k0 = kt << 6;
        // stage A: 128 rows x 64 k
        #pragma unroll
        for (int it = 0; it < 8; ++it) {
            int f = it * 256 + t;
            int row = f >> 4, kq = (f & 15) << 2;
            float4 av = make_float4(0.f, 0.f, 0.f, 0.f);
            if (bm + row < M && k0 + kq < K)
                av = *(const float4*)(A + (size_t)(bm + row) * lda + k0 + kq);
            ushort4 uv;
            uv.x = f2bf(av.x); uv.y = f2bf(av.y); uv.z = f2bf(av.z); uv.w = f2bf(av.w);
            *(ushort4*)(&As[row * 72 + kq]) = uv;
        }
        // stage B: GBN rows x 64 k
        #pragma unroll
        for (int it = 0; it < WJ * 2; ++it) {
            int f = it * 256 + t;
            int row = f >> 4, kq = (f & 15) << 2;
            float4 bv = make_float4(0.f, 0.f, 0.f, 0.f);
            if (bn + row < N && k0 + kq < K)
                bv = *(const float4*)(BT + (size_t)(bn + row) * ldb + k0 + kq);
            ushort4 uv;
            uv.x = f2bf(bv.x); uv.y = f2bf(bv.y); uv.z = f2bf(bv.z); uv.w = f2bf(bv.w);
            *(ushort4*)(&Bs[row * 72 + kq]) = uv;
        }
        __syncthreads();

        #pragma unroll
        for (int ks = 0; ks < 64; ks += 32) {
            short8 af[4], bfv[WJ];
            #pragma unroll
            for (int i = 0; i < 4; ++i)
                af[i] = *(const short8*)(&As[(wm + i * 16 + row16) * 72 + ks + quad * 8]);
            #pragma unroll
            for (int j = 0; j < WJ; ++j)
                bfv[j] = *(const short8*)(&Bs[(wn + j * 16 + row16) * 72 + ks + quad * 8]);
            #pragma unroll
            for (int i = 0; i < 4; ++i)
                #pragma unroll
                for (int j = 0; j < WJ; ++j)
                    acc[i][j] = __builtin_amdgcn_mfma_f32_16x16x32_bf16(af[i], bfv[j], acc[i][j], 0, 0, 0);
        }
        __syncthreads();
    }

    #pragma unroll
    for (int i = 0; i < 4; ++i)
        #pragma unroll
        for (int j = 0; j < WJ; ++j) {
            int col = bn + wn + j * 16 + row16;
            if (col >= N) continue;
            float bv = bias ? bias[col] : 0.f;
            #pragma unroll
            for (int r = 0; r < 4; ++r) {
                int row = bm + wm + i * 16 + quad * 4 + r;
                if (row < M) C[(size_t)row * ldc + col] = acc[i][j][r] + bv;
            }
        }
}

// ---------------- prep: transpose/concat all weight matrices ----------------
__global__ void prep_kernel(const float* __restrict__ Wq, const float* __restrict__ bq,
                            const float* __restrict__ Wqp, const float* __restrict__ bqp,
                            const float* __restrict__ Wb, const float* __restrict__ bb,
                            const float* __restrict__ Wdz, const float* __restrict__ bdz,
                            const float* __restrict__ Wks, const float* __restrict__ Wout,
                            float* __restrict__ wqqpT, float* __restrict__ bqqp,
                            float* __restrict__ wcatT, float* __restrict__ bcat,
                            float* __restrict__ wksT, float* __restrict__ woutT)
{
    int gid = blockIdx.x * 256 + threadIdx.x;
    int stride = gridDim.x * 256;
    for (int i = gid; i < 320 * 384; i += stride) {
        int o = i / 384, c = i % 384;
        wqqpT[i] = (o < 128) ? Wq[c * 128 + o] : Wqp[c * 192 + (o - 128)];
    }
    for (int i = gid; i < 320; i += stride) bqqp[i] = (i < 128) ? bq[i] : bqp[i - 128];
    for (int i = gid; i < 40 * 128; i += stride) {
        int o = i >> 7, c = i & 127;
        wcatT[i] = (o < 8) ? Wb[c * 8 + o] : Wdz[c * 32 + (o - 8)];
    }
    for (int i = gid; i < 40; i += stride) bcat[i] = (i < 8) ? bb[i] : bdz[i - 8];
    for (int i = gid; i < 128 * 128; i += stride) {
        int o = i >> 7, c = i & 127;
        wksT[i] = Wks[c * 128 + o];
    }
    for (int i = gid; i < 384 * 416; i += stride) {
        int o = i / 416, c = i % 416;
        woutT[i] = Wout[c * 384 + o];
    }
}

// ---------------- k_pts ----------------
__global__ void kpts_kernel(const float* __restrict__ tfn, const float* __restrict__ Wkv,
                            float* __restrict__ kpts, int n)
{
    int t = blockIdx.x * 256 + threadIdx.x;
    if (t >= n * 24) return;
    int node = t / 24, f = t % 24;
    int a = f >> 3;
    int b = f & 7;
    const float* vr = tfn + (size_t)node * 176 + 128;
    float s = 0.f;
    #pragma unroll
    for (int p = 0; p < 16; ++p) s += vr[p * 3 + a] * Wkv[p * 8 + b];
    kpts[t] = s;
}

// ---------------- q_pts rotation (qpraw has row stride 320, cols 128..319 of qqp) ----------------
__global__ void qpts_kernel(const float* __restrict__ qpraw, const float* __restrict__ rot,
                            const float* __restrict__ trans, float* __restrict__ qpts, int n)
{
    int t = blockIdx.x * 256 + threadIdx.x;
    if (t >= n * 64) return;
    int node = t / 64, hk = t % 64;
    const float* qr = qpraw + (size_t)node * 320;
    float r0 = qr[hk], r1 = qr[64 + hk], r2 = qr[128 + hk];
    const float* R = rot + (size_t)node * 9;
    const float* T = trans + (size_t)node * 3;
    float* o = qpts + (size_t)node * 192 + hk * 3;
    #pragma unroll
    for (int i = 0; i < 3; ++i)
        o[i] = R[i * 3 + 0] * r0 + R[i * 3 + 1] * r1 + R[i * 3 + 2] * r2 + T[i];
}

// ---------------- CSR build ----------------
__global__ void count_kernel(const int* __restrict__ srcA, int* __restrict__ cnt, int E)
{
    int e = blockIdx.x * 256 + threadIdx.x;
    if (e < E) atomicAdd(&cnt[srcA[e]], 1);
}

__global__ void scan_kernel(const int* __restrict__ cnt, int* __restrict__ off,
                            int* __restrict__ cur, int n)
{
    __shared__ int sums[1024];
    int t = threadIdx.x;
    int chunk = (n + 1023) >> 10;
    int begin = t * chunk;
    int local = 0;
    for (int j = 0; j < chunk; ++j) {
        int i = begin + j;
        if (i < n) local += cnt[i];
    }
    sums[t] = local;
    __syncthreads();
    for (int d = 1; d < 1024; d <<= 1) {
        int x = sums[t];
        int y = (t >= d) ? sums[t - d] : 0;
        __syncthreads();
        sums[t] = x + y;
        __syncthreads();
    }
    int run = sums[t] - local;
    for (int j = 0; j < chunk; ++j) {
        int i = begin + j;
        if (i < n) {
            off[i] = run;
            cur[i] = run;
            run += cnt[i];
        }
    }
}

__global__ void fill_kernel(const int* __restrict__ srcA, int* __restrict__ cur,
                            int* __restrict__ elist, int E)
{
    int e = blockIdx.x * 256 + threadIdx.x;
    if (e < E) {
        int s = srcA[e];
        int pos = atomicAdd(&cur[s], 1);
        elist[pos] = e;
    }
}

// ---------------- attention + aggregation + finalize: one wave per src node ----------------
// lane = es*8 + h : es = edge slot (0..7), h = head (0..7)
__global__ __launch_bounds__(256) void attn_kernel(
    const int* __restrict__ dstA,
    const int* __restrict__ off, const int* __restrict__ cnt, const int* __restrict__ elist,
    const float* __restrict__ qqp, const float* __restrict__ kbuf,
    const float* __restrict__ qpts, const float* __restrict__ kpts,
    const float* __restrict__ bpair, const float* __restrict__ mask,
    const float* __restrict__ hwin,
    const float* __restrict__ rot, const float* __restrict__ trans,
    float* __restrict__ feats, int n)
{
    int wave = threadIdx.x >> 6;
    int lane = threadIdx.x & 63;
    int s = blockIdx.x * 4 + wave;
    if (s >= n) return;
    int es = lane >> 3;
    int h  = lane & 7;

    float qh[16];
    {
        const float* qp = qqp + (size_t)s * 320 + h * 16;
        #pragma unroll
        for (int c = 0; c < 16; ++c) qh[c] = qp[c];
    }
    float qpt[24];
    {
        const float* pp = qpts + (size_t)s * 192 + h * 24;
        #pragma unroll
        for (int j = 0; j < 24; ++j) qpt[j] = pp[j];
    }
    float hwv = log1pf(__expf(hwin[h])) * 0.09622504486493764f;  // softplus * sqrt(1/108)
    float mask_s = mask[s];
    int myoff = off[s], mycnt = cnt[s];

    float ssum = 0.f;
    float oacc[16];
    #pragma unroll
    for (int c = 0; c < 16; ++c) oacc[c] = 0.f;
    float optacc[3] = {0.f, 0.f, 0.f};
    float opacc[8][4];
    #pragma unroll
    for (int j = 0; j < 8; ++j)
        #pragma unroll
        for (int c = 0; c < 4; ++c) opacc[j][c] = 0.f;

    int nb = (mycnt + 7) >> 3;
    for (int b = 0; b < nb; ++b) {
        int idx = b * 8 + es;
        bool valid = idx < mycnt;
        int e = valid ? elist[myoff + idx] : 0;
        int d = dstA[e];

        const float* kr = kbuf + (size_t)d * 128 + h * 16;
        float4 ka = *(const float4*)(kr + 0);
        float4 kb = *(const float4*)(kr + 4);
        float4 kc = *(const float4*)(kr + 8);
        float4 kd = *(const float4*)(kr + 12);

        const float* kp = kpts + (size_t)d * 24 + h * 3;
        float kp0 = kp[0], kp1 = kp[1], kp2 = kp[2];

        const float* bp = bpair + (size_t)e * 40;
        float bh = bp[h];
        float4 pair4 = *(const float4*)(bp + 8 + h * 4);

        float qk = qh[0] * ka.x + qh[1] * ka.y + qh[2] * ka.z + qh[3] * ka.w
                 + qh[4] * kb.x + qh[5] * kb.y + qh[6] * kb.z + qh[7] * kb.w
                 + qh[8] * kc.x + qh[9] * kc.y + qh[10] * kc.z + qh[11] * kc.w
                 + qh[12] * kd.x + qh[13] * kd.y + qh[14] * kd.z + qh[15] * kd.w;

        float pt = 0.f;
        #pragma unroll
        for (int pp = 0; pp < 8; ++pp) {
            float d0 = qpt[pp * 3 + 0] - kp0;
            float d1 = qpt[pp * 3 + 1] - kp1;
            float d2 = qpt[pp * 3 + 2] - kp2;
            pt += d0 * d0 + d1 * d1 + d2 * d2;
        }

        float md = mask[d];
        float logit = 0.14433756729740643f * qk
                    + 0.5773502691896258f * bh
                    - 0.5f * hwv * pt
                    + 100000.0f * (mask_s * md - 1.0f);
        float w = valid ? __expf(logit) : 0.f;

        ssum += w;
        oacc[0] += w * ka.x; oacc[1] += w * ka.y; oacc[2] += w * ka.z; oacc[3] += w * ka.w;
        oacc[4] += w * kb.x; oacc[5] += w * kb.y; oacc[6] += w * kb.z; oacc[7] += w * kb.w;
        oacc[8] += w * kc.x; oacc[9] += w * kc.y; oacc[10] += w * kc.z; oacc[11] += w * kc.w;
        oacc[12] += w * kd.x; oacc[13] += w * kd.y; oacc[14] += w * kd.z; oacc[15] += w * kd.w;
        optacc[0] += w * kp0;
        optacc[1] += w * kp1;
        optacc[2] += w * kp2;

        // o_pair: pair_z is head-independent -> broadcast w (1 shuffle per target head).
        // NOTE: opacc[jh] now accumulates with head jh's (unnormalized) weights.
        #pragma unroll
        for (int jh = 0; jh < 8; ++jh) {
            float wj = __shfl(w, (es << 3) + jh);
            opacc[jh][0] += wj * pair4.x;
            opacc[jh][1] += wj * pair4.y;
            opacc[jh][2] += wj * pair4.z;
            opacc[jh][3] += wj * pair4.w;
        }
    }

    // reduce across the 8 edge slots (lane bits 3..5)
    #pragma unroll
    for (int delta = 8; delta <= 32; delta <<= 1) {
        ssum += __shfl_xor(ssum, delta);
        #pragma unroll
        for (int c = 0; c < 16; ++c) oacc[c] += __shfl_xor(oacc[c], delta);
        #pragma unroll
        for (int i = 0; i < 3; ++i) optacc[i] += __shfl_xor(optacc[i], delta);
        #pragma unroll
        for (int j = 0; j < 8; ++j)
            #pragma unroll
            for (int c = 0; c < 4; ++c) opacc[j][c] += __shfl_xor(opacc[j][c], delta);
    }

    // Per-head denominators for o_pair: opacc[jh] was accumulated with head jh's
    // weights, so it must be normalized by head jh's sum (BUGFIX vs round 2).
    // Do the shuffles BEFORE the divergent branch so source registers are defined.
    float invj[8];
    #pragma unroll
    for (int jh = 0; jh < 8; ++jh)
        invj[jh] = 1.f / (__shfl(ssum, jh) + 1e-16f);

    if (es == 0) {
        float inv = 1.f / (ssum + 1e-16f);
        float* f = feats + (size_t)s * 416;
        // o -> f[0:128]
        #pragma unroll
        for (int c = 0; c < 16; c += 4) {
            float4 v = make_float4(oacc[c] * inv, oacc[c + 1] * inv, oacc[c + 2] * inv, oacc[c + 3] * inv);
            *(float4*)(&f[h * 16 + c]) = v;
        }
        // o_pt rotate back + norm -> f[128:160]
        const float* T = trans + (size_t)s * 3;
        const float* R = rot + (size_t)s * 9;
        float v0 = optacc[0] * inv - T[0];
        float v1 = optacc[1] * inv - T[1];
        float v2 = optacc[2] * inv - T[2];
        float r0 = R[0] * v0 + R[3] * v1 + R[6] * v2;
        float r1 = R[1] * v0 + R[4] * v1 + R[7] * v2;
        float r2 = R[2] * v0 + R[5] * v1 + R[8] * v2;
        f[128 + h] = r0;
        f[136 + h] = r1;
        f[144 + h] = r2;
        f[152 + h] = sqrtf(r0 * r0 + r1 * r1 + r2 * r2 + 1e-8f);
        // o_pair -> f[160:416]; lane h holds comps h*4..h*4+3 for every head jh
        #pragma unroll
        for (int jh = 0; jh < 8; ++jh) {
            float4 v = make_float4(opacc[jh][0] * invj[jh], opacc[jh][1] * invj[jh],
                                   opacc[jh][2] * invj[jh], opacc[jh][3] * invj[jh]);
            *(float4*)(&f[160 + jh * 32 + h * 4]) = v;
        }
    }
}

// ---------------- host ----------------
extern "C" void kernel_launch(void* const* d_in, const int* in_sizes, int n_in,
                              void* d_out, int out_size, void* d_ws, size_t ws_size,
                              hipStream_t stream)
{
    const float* frame_s = (const float*)d_in[0];
    const float* tfn     = (const float*)d_in[1];
    const float* z       = (const float*)d_in[2];
    const int*   ei      = (const int*)d_in[3];
    const float* mask    = (const float*)d_in[4];
    const float* rot     = (const float*)d_in[5];
    const float* trans   = (const float*)d_in[6];
    const float* Wq      = (const float*)d_in[7];
    const float* bq      = (const float*)d_in[8];
    const float* Wks     = (const float*)d_in[9];
    const float* Wkv     = (const float*)d_in[10];
    const float* Wqp     = (const float*)d_in[11];
    const float* bqp     = (const float*)d_in[12];
    const float* Wb      = (const float*)d_in[13];
    const float* bb      = (const float*)d_in[14];
    const float* Wdz     = (const float*)d_in[15];
    const float* bdz     = (const float*)d_in[16];
    const float* hw      = (const float*)d_in[17];
    const float* Wout    = (const float*)d_in[18];
    const float* bout    = (const float*)d_in[19];
    float* out = (float*)d_out;

    int n = in_sizes[0] / 384;
    int E = in_sizes[3] / 2;
    const int* dstA = ei;        // edge_index[0]
    const int* srcA = ei + E;    // edge_index[1]

    float* ws = (float*)d_ws;
    size_t p = 0;
    auto alloc = [&](size_t elems) -> float* {
        float* r = ws + p;
        p += (elems + 15) & ~((size_t)15);
        return r;
    };
    float* qqpbuf = alloc((size_t)n * 320);   // [q | qp_raw]
    float* qpts   = alloc((size_t)n * 192);
    float* kbuf   = alloc((size_t)n * 128);
    float* kpts   = alloc((size_t)n * 24);
    float* feats  = alloc((size_t)n * 416);
    float* bpair  = alloc((size_t)E * 40);
    float* wqqpT  = alloc(320 * 384);
    float* bqqp   = alloc(320);
    float* wcatT  = alloc(40 * 128);
    float* bcat   = alloc(64);
    float* wksT   = alloc(128 * 128);
    float* woutT  = alloc(384 * 416);
    int* cnt   = (int*)alloc((size_t)n);
    int* off   = (int*)alloc((size_t)n);
    int* cur   = (int*)alloc((size_t)n);
    int* elist = (int*)alloc((size_t)E);

    hipMemsetAsync(cnt, 0, (size_t)n * sizeof(int), stream);
    prep_kernel<<<512, 256, 0, stream>>>(Wq, bq, Wqp, bqp, Wb, bb, Wdz, bdz, Wks, Wout,
                                         wqqpT, bqqp, wcatT, bcat, wksT, woutT);

    count_kernel<<<(E + 255) / 256, 256, 0, stream>>>(srcA, cnt, E);
    scan_kernel<<<1, 1024, 0, stream>>>(cnt, off, cur, n);
    fill_kernel<<<(E + 255) / 256, 256, 0, stream>>>(srcA, cur, elist, E);

    {   // [q | qp_raw] = frame_s @ [Wq|Wqp] + [bq|bqp]
        dim3 g((n + 127) / 128, (320 + 127) / 128);
        gemm_mfma<4><<<g, 256, 0, stream>>>(frame_s, 384, wqqpT, 384, bqqp, qqpbuf, 320, n, 320, 384);
    }
    {   // k = tfn[:, :128] @ Wk_s
        dim3 g((n + 127) / 128, 1);
        gemm_mfma<4><<<g, 256, 0, stream>>>(tfn, 176, wksT, 128, nullptr, kbuf, 128, n, 128, 128);
    }
    {   // bpair = z @ [Wb|Wdz] + [bb|bdz]   (N=40 -> 64-wide variant)
        dim3 g((E + 127) / 128, 1);
        gemm_mfma<2><<<g, 256, 0, stream>>>(z, 128, wcatT, 128, bcat, bpair, 40, E, 40, 128);
    }
    kpts_kernel<<<(n * 24 + 255) / 256, 256, 0, stream>>>(tfn, Wkv, kpts, n);
    qpts_kernel<<<(n * 64 + 255) / 256, 256, 0, stream>>>(qqpbuf + 128, rot, trans, qpts, n);

    attn_kernel<<<(n + 3) / 4, 256, 0, stream>>>(dstA, off, cnt, elist,
                                                 qqpbuf, kbuf, qpts, kpts, bpair, mask, hw,
                                                 rot, trans, feats, n);

    {   // out = feats @ Wout + bout
        dim3 g((n + 127) / 128, (384 + 127) / 128);
        gemm_mfma<4><<<g, 256, 0, stream>>>(feats, 416, woutT, 416, bout, out, 384, n, 384, 416);
    }
    (void)n_in; (void)out_size; (void)ws_size;
}